// Round 5
// baseline (1569.658 us; speedup 1.0000x reference)
//
#include <hip/hip_runtime.h>
#include <hip/hip_cooperative_groups.h>
#include <math.h>

namespace cg = cooperative_groups;

#define B    4
#define T    16384
#define A    256
#define K    256
#define PAD  128
#define TP   (T + 2*PAD)      // 16640
#define TOUT (TP - K + 1)     // 16385
#define ITERS 16
#define CHUNK 512
#define NCHUNK 33
#define NCP  36               // padded per-atom chunk stride
#define TILE 2048
#define NTILE 9
#define NBLK 512              // block owns atoms (2*a0, 2*a0+1) of batch b

struct Smem {
    float rp[TILE + K + 16];  // 2320 floats
    float dnA[K];
    float dnB[K];
    float dnsel[K];
    float wv[16]; int wi[16];
    float fv; int fi;
};

#define TAP(acc, s0,s1,s2,s3, dq) { acc = fmaf(s0,(dq).x,acc); acc = fmaf(s1,(dq).y,acc); \
                                    acc = fmaf(s2,(dq).z,acc); acc = fmaf(s3,(dq).w,acc); }

__device__ __forceinline__ void wave_amax(float& bv, int& bi) {
    #pragma unroll
    for (int off = 32; off; off >>= 1) {
        float ov = __shfl_down(bv, off);
        int   oi = __shfl_down(bi, off);
        if (ov > bv || (ov == bv && oi < bi)) { bv = ov; bi = oi; }
    }
}

// ---------- phase 0: normalize (blocks 0..127 handle atoms 2a0,2a0+1) + init ----------
__device__ __forceinline__ void dev_norm(int bid, int tid, const float* __restrict__ d,
                                         float* __restrict__ dn, Smem& sm) {
    if (bid < 128) {
        int lane = tid & 63, w = tid >> 6;
        #pragma unroll
        for (int s = 0; s < 2; s++) {
            int atom = (bid & 127)*2 + s;
            float v = d[atom*K + tid];
            float sq = v*v;
            #pragma unroll
            for (int off = 32; off; off >>= 1) sq += __shfl_down(sq, off);
            if (lane == 0) sm.wv[w] = sq;
            __syncthreads();
            float norm = sqrtf(sm.wv[0] + sm.wv[1] + sm.wv[2] + sm.wv[3]) + 1e-12f;
            dn[atom*K + tid] = v / norm;
            __syncthreads();
        }
    }
}

__device__ __forceinline__ void dev_init(int bid, int tid, const float* __restrict__ x,
                                         float* __restrict__ rp, float* __restrict__ recon) {
    for (int i = bid*256 + tid; i < B*TP; i += NBLK*256) {
        int bb = i / TP, t = i - bb*TP;
        float v = (t >= PAD && t < PAD + T) ? x[bb*T + (t - PAD)] : 0.f;
        rp[i] = v;
        recon[i] = 0.f;
    }
}

// ---------- phase 1: full conv for 2 atoms, chunk maxima -> segval, atom best -> abv ----
__device__ void dev_conv(int a0, int b, int tid, const float* __restrict__ rp,
                         const float* __restrict__ dn,
                         float* __restrict__ segval, int* __restrict__ segidx,
                         float* __restrict__ abv, int* __restrict__ abi, Smem& sm) {
    const int aA = a0*2, aB = a0*2 + 1;
    const int lane = tid & 63, w = tid >> 6;
    sm.dnA[tid] = dn[aA*K + tid];
    sm.dnB[tid] = dn[aB*K + tid];
    const float4* rp4 = (const float4*)(rp + (size_t)b*TP);

    for (int tile = 0; tile < NTILE; tile++) {
        int t0 = tile * TILE;
        __syncthreads();
        float4* s4 = (float4*)sm.rp;
        for (int i = tid; i < 580; i += 256) {
            int g = t0/4 + i;
            float4 v = {0.f,0.f,0.f,0.f};
            if (g*4 < TP) v = rp4[g];
            s4[i] = v;
        }
        __syncthreads();
        const float4* srp4 = (const float4*)sm.rp;
        const float4* dA4  = (const float4*)sm.dnA;
        const float4* dB4  = (const float4*)sm.dnB;
        float accA0[4] = {0,0,0,0}, accA1[4] = {0,0,0,0};
        float accB0[4] = {0,0,0,0}, accB1[4] = {0,0,0,0};
        float4 p = srp4[tid];
        float4 q = srp4[tid + 256];
        #pragma unroll 4
        for (int kq = 0; kq < 64; kq++) {
            float4 dA = dA4[kq];
            float4 dB = dB4[kq];
            float4 pn = srp4[tid + kq + 1];
            float4 qn = srp4[tid + 256 + kq + 1];
            TAP(accA0[0], p.x,p.y,p.z,p.w, dA); TAP(accA0[1], p.y,p.z,p.w,pn.x, dA);
            TAP(accA0[2], p.z,p.w,pn.x,pn.y, dA); TAP(accA0[3], p.w,pn.x,pn.y,pn.z, dA);
            TAP(accB0[0], p.x,p.y,p.z,p.w, dB); TAP(accB0[1], p.y,p.z,p.w,pn.x, dB);
            TAP(accB0[2], p.z,p.w,pn.x,pn.y, dB); TAP(accB0[3], p.w,pn.x,pn.y,pn.z, dB);
            TAP(accA1[0], q.x,q.y,q.z,q.w, dA); TAP(accA1[1], q.y,q.z,q.w,qn.x, dA);
            TAP(accA1[2], q.z,q.w,qn.x,qn.y, dA); TAP(accA1[3], q.w,qn.x,qn.y,qn.z, dA);
            TAP(accB1[0], q.x,q.y,q.z,q.w, dB); TAP(accB1[1], q.y,q.z,q.w,qn.x, dB);
            TAP(accB1[2], q.z,q.w,qn.x,qn.y, dB); TAP(accB1[3], q.w,qn.x,qn.y,qn.z, dB);
            p = pn; q = qn;
        }
        int lt = tid * 4;
        float bvA0 = -INFINITY, bvA1 = -INFINITY, bvB0 = -INFINITY, bvB1 = -INFINITY;
        int biA0 = 0x7fffffff, biA1 = 0x7fffffff, biB0 = 0x7fffffff, biB1 = 0x7fffffff;
        #pragma unroll
        for (int j = 0; j < 4; j++) {
            int t = t0 + lt + j;
            if (t < TOUT) {
                if (accA0[j] > bvA0) { bvA0 = accA0[j]; biA0 = aA*TOUT + t; }
                if (accB0[j] > bvB0) { bvB0 = accB0[j]; biB0 = aB*TOUT + t; }
            }
            int t1 = t0 + 1024 + lt + j;
            if (t1 < TOUT) {
                if (accA1[j] > bvA1) { bvA1 = accA1[j]; biA1 = aA*TOUT + t1; }
                if (accB1[j] > bvB1) { bvB1 = accB1[j]; biB1 = aB*TOUT + t1; }
            }
        }
        wave_amax(bvA0, biA0); wave_amax(bvA1, biA1);
        wave_amax(bvB0, biB0); wave_amax(bvB1, biB1);
        if (lane == 0) {
            sm.wv[w]    = bvA0; sm.wi[w]    = biA0;
            sm.wv[4+w]  = bvA1; sm.wi[4+w]  = biA1;
            sm.wv[8+w]  = bvB0; sm.wi[8+w]  = biB0;
            sm.wv[12+w] = bvB1; sm.wi[12+w] = biB1;
        }
        __syncthreads();
        // chunk c (0..3 in tile): partial pair (2c, 2c+1); atom B at +8
        if (tid < 4) {
            float v0 = sm.wv[2*tid];   int i0 = sm.wi[2*tid];
            float v1 = sm.wv[2*tid+1]; int i1 = sm.wi[2*tid+1];
            if (v1 > v0 || (v1 == v0 && i1 < i0)) { v0 = v1; i0 = i1; }
            int chunk = tile*4 + tid;
            if (chunk < NCHUNK) {
                segval[((size_t)b*A + aA)*NCP + chunk] = v0;
                segidx[((size_t)b*A + aA)*NCP + chunk] = i0;
            }
        } else if (tid >= 64 && tid < 68) {
            int c = tid - 64;
            float v0 = sm.wv[8+2*c];   int i0 = sm.wi[8+2*c];
            float v1 = sm.wv[8+2*c+1]; int i1 = sm.wi[8+2*c+1];
            if (v1 > v0 || (v1 == v0 && i1 < i0)) { v0 = v1; i0 = i1; }
            int chunk = tile*4 + c;
            if (chunk < NCHUNK) {
                segval[((size_t)b*A + aB)*NCP + chunk] = v0;
                segidx[((size_t)b*A + aB)*NCP + chunk] = i0;
            }
        }
    }
    __syncthreads();
    // per-atom best over 33 chunks (wave0 -> atom A, wave1 -> atom B)
    if (w < 2) {
        int atom = (w == 0) ? aA : aB;
        float bv = -INFINITY; int bi = 0x7fffffff;
        if (lane < NCHUNK) {
            bv = segval[((size_t)b*A + atom)*NCP + lane];
            bi = segidx[((size_t)b*A + atom)*NCP + lane];
        }
        wave_amax(bv, bi);
        if (lane == 0) { abv[b*A + atom] = bv; abi[b*A + atom] = bi; }
    }
}

// ---------- one matching-pursuit iteration ----------
__device__ void dev_iter(int a0, int b, int tid, int last,
                         const float* __restrict__ avc, const int* __restrict__ aic,
                         float* __restrict__ avn, int* __restrict__ ain,
                         const float* __restrict__ rin, float* __restrict__ rout,
                         float* __restrict__ recon, const float* __restrict__ dn,
                         float* __restrict__ segval, int* __restrict__ segidx, Smem& sm) {
    const int aA = a0*2, aB = a0*2 + 1;
    const int lane = tid & 63, w = tid >> 6;
    sm.dnA[tid] = dn[aA*K + tid];
    sm.dnB[tid] = dn[aB*K + tid];
    // pick (redundant, deterministic across blocks of batch b)
    {
        float bv = avc[b*A + tid]; int bi = aic[b*A + tid];
        wave_amax(bv, bi);
        if (lane == 0) { sm.wv[w] = bv; sm.wi[w] = bi; }
        __syncthreads();
        if (tid == 0) {
            bv = sm.wv[0]; bi = sm.wi[0];
            for (int j = 1; j < 4; j++)
                if (sm.wv[j] > bv || (sm.wv[j] == bv && sm.wi[j] < bi)) { bv = sm.wv[j]; bi = sm.wi[j]; }
            sm.fv = bv; sm.fi = bi;
        }
        __syncthreads();
    }
    float val = sm.fv; int idx = sm.fi;
    int atom = idx / TOUT, pos = idx - atom*TOUT;
    sm.dnsel[tid] = dn[atom*K + tid];

    int lo = pos - (K-1); if (lo < 0) lo = 0;
    int c_lo = lo >> 9;
    int tbase = c_lo * CHUNK;

    if (!last) {   // stage window [tbase, tbase+1296)
        const float4* rin4 = (const float4*)(rin + (size_t)b*TP);
        float4* s4 = (float4*)sm.rp;
        for (int i = tid; i < 324; i += 256) {
            int g = tbase/4 + i;
            float4 v = {0.f,0.f,0.f,0.f};
            if (g*4 < TP) v = rin4[g];
            s4[i] = v;
        }
    }
    __syncthreads();
    if (a0 == 0) {   // designated writer per batch: rout row + recon
        if (!last) {
            const float4* rin4 = (const float4*)(rin + (size_t)b*TP);
            float4* rout4 = (float4*)(rout + (size_t)b*TP);
            for (int i = tid; i < TP/4; i += 256) {
                float4 v = rin4[i];
                int o = i*4 - pos;
                if (o > -4 && o < K) {
                    if (o+0 >= 0 && o+0 < K) v.x -= val * sm.dnsel[o+0];
                    if (o+1 >= 0 && o+1 < K) v.y -= val * sm.dnsel[o+1];
                    if (o+2 >= 0 && o+2 < K) v.z -= val * sm.dnsel[o+2];
                    if (o+3 >= 0 && o+3 < K) v.w -= val * sm.dnsel[o+3];
                }
                rout4[i] = v;
            }
        }
        recon[(size_t)b*TP + pos + tid] += val * sm.dnsel[tid];
    }
    if (last) return;

    // apply update delta in LDS (changed region [pos, pos+K) maps into the window)
    sm.rp[pos + tid - tbase] -= val * sm.dnsel[tid];
    __syncthreads();

    // recompute 1024 outputs [tbase, tbase+1024) for both atoms
    const float4* srp4 = (const float4*)sm.rp;
    const float4* dA4  = (const float4*)sm.dnA;
    const float4* dB4  = (const float4*)sm.dnB;
    float cA[4] = {0,0,0,0}, cB[4] = {0,0,0,0};
    float4 p = srp4[tid];
    #pragma unroll 4
    for (int kq = 0; kq < 64; kq++) {
        float4 dA = dA4[kq];
        float4 dB = dB4[kq];
        float4 pn = srp4[tid + kq + 1];
        TAP(cA[0], p.x,p.y,p.z,p.w, dA); TAP(cA[1], p.y,p.z,p.w,pn.x, dA);
        TAP(cA[2], p.z,p.w,pn.x,pn.y, dA); TAP(cA[3], p.w,pn.x,pn.y,pn.z, dA);
        TAP(cB[0], p.x,p.y,p.z,p.w, dB); TAP(cB[1], p.y,p.z,p.w,pn.x, dB);
        TAP(cB[2], p.z,p.w,pn.x,pn.y, dB); TAP(cB[3], p.w,pn.x,pn.y,pn.z, dB);
        p = pn;
    }
    int lt = tid * 4;
    float bvA = -INFINITY, bvB = -INFINITY;
    int biA = 0x7fffffff, biB = 0x7fffffff;
    #pragma unroll
    for (int j = 0; j < 4; j++) {
        int t = tbase + lt + j;
        if (t < TOUT) {
            if (cA[j] > bvA) { bvA = cA[j]; biA = aA*TOUT + t; }
            if (cB[j] > bvB) { bvB = cB[j]; biB = aB*TOUT + t; }
        }
    }
    wave_amax(bvA, biA); wave_amax(bvB, biB);
    if (lane == 0) { sm.wv[w] = bvA; sm.wi[w] = biA; sm.wv[8+w] = bvB; sm.wi[8+w] = biB; }
    __syncthreads();
    if (tid < 2) {         // atom A: chunk c_lo + tid <- waves (2*tid, 2*tid+1)
        float v0 = sm.wv[2*tid];   int i0 = sm.wi[2*tid];
        float v1 = sm.wv[2*tid+1]; int i1 = sm.wi[2*tid+1];
        if (v1 > v0 || (v1 == v0 && i1 < i0)) { v0 = v1; i0 = i1; }
        int chunk = c_lo + tid;
        if (chunk < NCHUNK) {
            segval[((size_t)b*A + aA)*NCP + chunk] = v0;
            segidx[((size_t)b*A + aA)*NCP + chunk] = i0;
        }
    } else if (tid >= 64 && tid < 66) {
        int c = tid - 64;
        float v0 = sm.wv[8+2*c];   int i0 = sm.wi[8+2*c];
        float v1 = sm.wv[8+2*c+1]; int i1 = sm.wi[8+2*c+1];
        if (v1 > v0 || (v1 == v0 && i1 < i0)) { v0 = v1; i0 = i1; }
        int chunk = c_lo + c;
        if (chunk < NCHUNK) {
            segval[((size_t)b*A + aB)*NCP + chunk] = v0;
            segidx[((size_t)b*A + aB)*NCP + chunk] = i0;
        }
    }
    __syncthreads();
    // refresh per-atom best over all 33 chunks
    if (w < 2) {
        int at = (w == 0) ? aA : aB;
        float bv = -INFINITY; int bi = 0x7fffffff;
        if (lane < NCHUNK) {
            bv = segval[((size_t)b*A + at)*NCP + lane];
            bi = segidx[((size_t)b*A + at)*NCP + lane];
        }
        wave_amax(bv, bi);
        if (lane == 0) { avn[b*A + at] = bv; ain[b*A + at] = bi; }
    }
}

// ================= cooperative single-kernel path =================
__global__ void __launch_bounds__(256, 4)
k_coop(const float* __restrict__ x, const float* __restrict__ d, float* __restrict__ out,
       float* __restrict__ dn, float* __restrict__ rp0, float* __restrict__ rp1,
       float* __restrict__ recon, float* __restrict__ segval, int* __restrict__ segidx,
       float* __restrict__ abv0, int* __restrict__ abi0,
       float* __restrict__ abv1, int* __restrict__ abi1) {
    cg::grid_group grid = cg::this_grid();
    __shared__ Smem sm;
    const int bid = blockIdx.x, tid = threadIdx.x;
    const int a0 = bid & 127, b = bid >> 7;
    dev_norm(bid, tid, d, dn, sm);
    dev_init(bid, tid, x, rp0, recon);
    grid.sync();
    dev_conv(a0, b, tid, rp0, dn, segval, segidx, abv0, abi0, sm);
    grid.sync();
    const float* rin = rp0; float* rout = rp1;
    const float* avc = abv0; const int* aic = abi0;
    float* avn = abv1; int* ain = abi1;
    for (int it = 0; it < ITERS; it++) {
        dev_iter(a0, b, tid, it == ITERS-1, avc, aic, avn, ain,
                 rin, rout, recon, dn, segval, segidx, sm);
        { const float* t1 = rin; rin = rout; rout = (float*)t1; }
        { const float* t2 = avc; avc = avn; avn = (float*)t2; }
        { const int*   t3 = aic; aic = ain; ain = (int*)t3; }
        grid.sync();
    }
    for (int i = bid*256 + tid; i < B*T; i += NBLK*256) {
        int bb = i / T, t = i - bb*T;
        out[i] = recon[(size_t)bb*TP + PAD + t];
    }
}

// ================= non-cooperative fallback path =================
__global__ void __launch_bounds__(256) k_f_norm_init(const float* x, const float* d,
                                                     float* dn, float* rp0, float* recon) {
    __shared__ Smem sm;
    dev_norm(blockIdx.x, threadIdx.x, d, dn, sm);
    dev_init(blockIdx.x, threadIdx.x, x, rp0, recon);
}
__global__ void __launch_bounds__(256, 4) k_f_conv(const float* rp, const float* dn,
                                                   float* segval, int* segidx,
                                                   float* abv, int* abi) {
    __shared__ Smem sm;
    dev_conv(blockIdx.x & 127, blockIdx.x >> 7, threadIdx.x, rp, dn, segval, segidx, abv, abi, sm);
}
__global__ void __launch_bounds__(256, 4) k_f_iter(int last,
                                                   const float* avc, const int* aic,
                                                   float* avn, int* ain,
                                                   const float* rin, float* rout,
                                                   float* recon, const float* dn,
                                                   float* segval, int* segidx) {
    __shared__ Smem sm;
    dev_iter(blockIdx.x & 127, blockIdx.x >> 7, threadIdx.x, last,
             avc, aic, avn, ain, rin, rout, recon, dn, segval, segidx, sm);
}
__global__ void k_f_out(const float* recon, float* out) {
    int i = blockIdx.x * blockDim.x + threadIdx.x;
    if (i >= B*T) return;
    int b = i / T, t = i - b*T;
    out[i] = recon[(size_t)b*TP + PAD + t];
}

extern "C" void kernel_launch(void* const* d_in, const int* in_sizes, int n_in,
                              void* d_out, int out_size, void* d_ws, size_t ws_size,
                              hipStream_t stream) {
    const float* x = (const float*)d_in[0];
    const float* d = (const float*)d_in[1];
    float* out = (float*)d_out;

    float* ws     = (float*)d_ws;
    float* dn     = ws;                                   // A*K
    float* rp0    = dn  + (size_t)A*K;                    // B*TP
    float* rp1    = rp0 + (size_t)B*TP;                   // B*TP
    float* recon  = rp1 + (size_t)B*TP;                   // B*TP
    float* segval = recon + (size_t)B*TP;                 // B*A*NCP
    int*   segidx = (int*)(segval + (size_t)B*A*NCP);     // B*A*NCP
    float* abv0   = (float*)(segidx + (size_t)B*A*NCP);   // B*A
    float* abv1   = abv0 + (size_t)B*A;                   // B*A
    int*   abi0   = (int*)(abv1 + (size_t)B*A);           // B*A
    int*   abi1   = abi0 + (size_t)B*A;                   // B*A

    // deterministic cooperative-launch feasibility check (host queries only)
    int nb = 0, ncu = 0;
    hipError_t e1 = hipOccupancyMaxActiveBlocksPerMultiprocessor(&nb, (const void*)k_coop, 256, 0);
    hipError_t e2 = hipDeviceGetAttribute(&ncu, hipDeviceAttributeMultiprocessorCount, 0);
    bool coop = (e1 == hipSuccess && e2 == hipSuccess && nb > 0 && ncu > 0 &&
                 (long)nb * ncu >= NBLK);
    if (coop) {
        void* args[] = {(void*)&x, (void*)&d, (void*)&out, (void*)&dn,
                        (void*)&rp0, (void*)&rp1, (void*)&recon,
                        (void*)&segval, (void*)&segidx,
                        (void*)&abv0, (void*)&abi0, (void*)&abv1, (void*)&abi1};
        hipError_t e = hipLaunchCooperativeKernel((const void*)k_coop, dim3(NBLK), dim3(256),
                                                  args, 0, stream);
        if (e == hipSuccess) return;
    }
    // fallback: same device code, separate launches, double-buffered (race-free)
    k_f_norm_init<<<NBLK, 256, 0, stream>>>(x, d, dn, rp0, recon);
    k_f_conv<<<NBLK, 256, 0, stream>>>(rp0, dn, segval, segidx, abv0, abi0);
    float* rbuf[2] = {rp0, rp1};
    float* av[2]   = {abv0, abv1};
    int*   ai[2]   = {abi0, abi1};
    for (int it = 0; it < ITERS; it++) {
        k_f_iter<<<NBLK, 256, 0, stream>>>(it == ITERS-1 ? 1 : 0,
                                           av[it & 1], ai[it & 1],
                                           av[(it + 1) & 1], ai[(it + 1) & 1],
                                           rbuf[it & 1], rbuf[(it + 1) & 1],
                                           recon, dn, segval, segidx);
    }
    k_f_out<<<(B*T + 255)/256, 256, 0, stream>>>(recon, out);
}

// Round 6
// 584.414 us; speedup vs baseline: 2.6859x; 2.6859x over previous
//
#include <hip/hip_runtime.h>
#include <hip/hip_cooperative_groups.h>
#include <math.h>

namespace cg = cooperative_groups;

#define B    4
#define T    16384
#define A    256
#define K    256
#define PAD  128
#define TP   (T + 2*PAD)      // 16640
#define TOUT (TP - K + 1)     // 16385
#define ITERS 16
#define CHUNK 512
#define NCHUNK 33
#define NCP  36               // padded per-atom chunk stride
#define TILE 2048
#define NTILE 9
#define NBLK 512              // block owns atoms (2*a0, 2*a0+1) of batch b

struct Smem {
    float rp[TILE + K + 16];  // 2320 floats
    float dnA[K];
    float dnB[K];
    float dnsel[K];
    float wv[16]; int wi[16];
    float fv; int fi;
};

#define TAP(acc, s0,s1,s2,s3, dq) { acc = fmaf(s0,(dq).x,acc); acc = fmaf(s1,(dq).y,acc); \
                                    acc = fmaf(s2,(dq).z,acc); acc = fmaf(s3,(dq).w,acc); }

__device__ __forceinline__ void wave_amax(float& bv, int& bi) {
    #pragma unroll
    for (int off = 32; off; off >>= 1) {
        float ov = __shfl_down(bv, off);
        int   oi = __shfl_down(bi, off);
        if (ov > bv || (ov == bv && oi < bi)) { bv = ov; bi = oi; }
    }
}

// ---------- phase 0: normalize (blocks 0..127 handle atoms 2a0,2a0+1) + init ----------
__device__ __forceinline__ void dev_norm(int bid, int tid, const float* __restrict__ d,
                                         float* __restrict__ dn, Smem& sm) {
    if (bid < 128) {
        int lane = tid & 63, w = tid >> 6;
        #pragma unroll
        for (int s = 0; s < 2; s++) {
            int atom = (bid & 127)*2 + s;
            float v = d[atom*K + tid];
            float sq = v*v;
            #pragma unroll
            for (int off = 32; off; off >>= 1) sq += __shfl_down(sq, off);
            if (lane == 0) sm.wv[w] = sq;
            __syncthreads();
            float norm = sqrtf(sm.wv[0] + sm.wv[1] + sm.wv[2] + sm.wv[3]) + 1e-12f;
            dn[atom*K + tid] = v / norm;
            __syncthreads();
        }
    }
}

__device__ __forceinline__ void dev_init(int bid, int tid, const float* __restrict__ x,
                                         float* __restrict__ rp, float* __restrict__ recon) {
    for (int i = bid*256 + tid; i < B*TP; i += NBLK*256) {
        int bb = i / TP, t = i - bb*TP;
        float v = (t >= PAD && t < PAD + T) ? x[bb*T + (t - PAD)] : 0.f;
        rp[i] = v;
        recon[i] = 0.f;
    }
}

// ---------- phase 1: full conv for 2 atoms, chunk maxima -> segval, atom best -> abv ----
__device__ void dev_conv(int a0, int b, int tid, const float* __restrict__ rp,
                         const float* __restrict__ dn,
                         float* __restrict__ segval, int* __restrict__ segidx,
                         float* __restrict__ abv, int* __restrict__ abi, Smem& sm) {
    const int aA = a0*2, aB = a0*2 + 1;
    const int lane = tid & 63, w = tid >> 6;
    sm.dnA[tid] = dn[aA*K + tid];
    sm.dnB[tid] = dn[aB*K + tid];
    const float4* rp4 = (const float4*)(rp + (size_t)b*TP);

    for (int tile = 0; tile < NTILE; tile++) {
        int t0 = tile * TILE;
        __syncthreads();
        float4* s4 = (float4*)sm.rp;
        for (int i = tid; i < 580; i += 256) {
            int g = t0/4 + i;
            float4 v = {0.f,0.f,0.f,0.f};
            if (g*4 < TP) v = rp4[g];
            s4[i] = v;
        }
        __syncthreads();
        const float4* srp4 = (const float4*)sm.rp;
        const float4* dA4  = (const float4*)sm.dnA;
        const float4* dB4  = (const float4*)sm.dnB;
        float accA0[4] = {0,0,0,0}, accA1[4] = {0,0,0,0};
        float accB0[4] = {0,0,0,0}, accB1[4] = {0,0,0,0};
        float4 p = srp4[tid];
        float4 q = srp4[tid + 256];
        #pragma unroll 4
        for (int kq = 0; kq < 64; kq++) {
            float4 dA = dA4[kq];
            float4 dB = dB4[kq];
            float4 pn = srp4[tid + kq + 1];
            float4 qn = srp4[tid + 256 + kq + 1];
            TAP(accA0[0], p.x,p.y,p.z,p.w, dA); TAP(accA0[1], p.y,p.z,p.w,pn.x, dA);
            TAP(accA0[2], p.z,p.w,pn.x,pn.y, dA); TAP(accA0[3], p.w,pn.x,pn.y,pn.z, dA);
            TAP(accB0[0], p.x,p.y,p.z,p.w, dB); TAP(accB0[1], p.y,p.z,p.w,pn.x, dB);
            TAP(accB0[2], p.z,p.w,pn.x,pn.y, dB); TAP(accB0[3], p.w,pn.x,pn.y,pn.z, dB);
            TAP(accA1[0], q.x,q.y,q.z,q.w, dA); TAP(accA1[1], q.y,q.z,q.w,qn.x, dA);
            TAP(accA1[2], q.z,q.w,qn.x,qn.y, dA); TAP(accA1[3], q.w,qn.x,qn.y,qn.z, dA);
            TAP(accB1[0], q.x,q.y,q.z,q.w, dB); TAP(accB1[1], q.y,q.z,q.w,qn.x, dB);
            TAP(accB1[2], q.z,q.w,qn.x,qn.y, dB); TAP(accB1[3], q.w,qn.x,qn.y,qn.z, dB);
            p = pn; q = qn;
        }
        int lt = tid * 4;
        float bvA0 = -INFINITY, bvA1 = -INFINITY, bvB0 = -INFINITY, bvB1 = -INFINITY;
        int biA0 = 0x7fffffff, biA1 = 0x7fffffff, biB0 = 0x7fffffff, biB1 = 0x7fffffff;
        #pragma unroll
        for (int j = 0; j < 4; j++) {
            int t = t0 + lt + j;
            if (t < TOUT) {
                if (accA0[j] > bvA0) { bvA0 = accA0[j]; biA0 = aA*TOUT + t; }
                if (accB0[j] > bvB0) { bvB0 = accB0[j]; biB0 = aB*TOUT + t; }
            }
            int t1 = t0 + 1024 + lt + j;
            if (t1 < TOUT) {
                if (accA1[j] > bvA1) { bvA1 = accA1[j]; biA1 = aA*TOUT + t1; }
                if (accB1[j] > bvB1) { bvB1 = accB1[j]; biB1 = aB*TOUT + t1; }
            }
        }
        wave_amax(bvA0, biA0); wave_amax(bvA1, biA1);
        wave_amax(bvB0, biB0); wave_amax(bvB1, biB1);
        if (lane == 0) {
            sm.wv[w]    = bvA0; sm.wi[w]    = biA0;
            sm.wv[4+w]  = bvA1; sm.wi[4+w]  = biA1;
            sm.wv[8+w]  = bvB0; sm.wi[8+w]  = biB0;
            sm.wv[12+w] = bvB1; sm.wi[12+w] = biB1;
        }
        __syncthreads();
        // chunk c (0..3 in tile): partial pair (2c, 2c+1); atom B at +8
        if (tid < 4) {
            float v0 = sm.wv[2*tid];   int i0 = sm.wi[2*tid];
            float v1 = sm.wv[2*tid+1]; int i1 = sm.wi[2*tid+1];
            if (v1 > v0 || (v1 == v0 && i1 < i0)) { v0 = v1; i0 = i1; }
            int chunk = tile*4 + tid;
            if (chunk < NCHUNK) {
                segval[((size_t)b*A + aA)*NCP + chunk] = v0;
                segidx[((size_t)b*A + aA)*NCP + chunk] = i0;
            }
        } else if (tid >= 64 && tid < 68) {
            int c = tid - 64;
            float v0 = sm.wv[8+2*c];   int i0 = sm.wi[8+2*c];
            float v1 = sm.wv[8+2*c+1]; int i1 = sm.wi[8+2*c+1];
            if (v1 > v0 || (v1 == v0 && i1 < i0)) { v0 = v1; i0 = i1; }
            int chunk = tile*4 + c;
            if (chunk < NCHUNK) {
                segval[((size_t)b*A + aB)*NCP + chunk] = v0;
                segidx[((size_t)b*A + aB)*NCP + chunk] = i0;
            }
        }
    }
    __syncthreads();
    // per-atom best over 33 chunks (wave0 -> atom A, wave1 -> atom B)
    if (w < 2) {
        int atom = (w == 0) ? aA : aB;
        float bv = -INFINITY; int bi = 0x7fffffff;
        if (lane < NCHUNK) {
            bv = segval[((size_t)b*A + atom)*NCP + lane];
            bi = segidx[((size_t)b*A + atom)*NCP + lane];
        }
        wave_amax(bv, bi);
        if (lane == 0) { abv[b*A + atom] = bv; abi[b*A + atom] = bi; }
    }
}

// ---------- one matching-pursuit iteration ----------
__device__ void dev_iter(int a0, int b, int tid, int last,
                         const float* __restrict__ avc, const int* __restrict__ aic,
                         float* __restrict__ avn, int* __restrict__ ain,
                         const float* __restrict__ rin, float* __restrict__ rout,
                         float* __restrict__ recon, const float* __restrict__ dn,
                         float* __restrict__ segval, int* __restrict__ segidx, Smem& sm) {
    const int aA = a0*2, aB = a0*2 + 1;
    const int lane = tid & 63, w = tid >> 6;
    sm.dnA[tid] = dn[aA*K + tid];
    sm.dnB[tid] = dn[aB*K + tid];
    // pick (redundant, deterministic across blocks of batch b)
    {
        float bv = avc[b*A + tid]; int bi = aic[b*A + tid];
        wave_amax(bv, bi);
        if (lane == 0) { sm.wv[w] = bv; sm.wi[w] = bi; }
        __syncthreads();
        if (tid == 0) {
            bv = sm.wv[0]; bi = sm.wi[0];
            for (int j = 1; j < 4; j++)
                if (sm.wv[j] > bv || (sm.wv[j] == bv && sm.wi[j] < bi)) { bv = sm.wv[j]; bi = sm.wi[j]; }
            sm.fv = bv; sm.fi = bi;
        }
        __syncthreads();
    }
    float val = sm.fv; int idx = sm.fi;
    int atom = idx / TOUT, pos = idx - atom*TOUT;
    sm.dnsel[tid] = dn[atom*K + tid];

    int lo = pos - (K-1); if (lo < 0) lo = 0;
    int c_lo = lo >> 9;
    int tbase = c_lo * CHUNK;

    if (!last) {   // stage window [tbase, tbase+1296)
        const float4* rin4 = (const float4*)(rin + (size_t)b*TP);
        float4* s4 = (float4*)sm.rp;
        for (int i = tid; i < 324; i += 256) {
            int g = tbase/4 + i;
            float4 v = {0.f,0.f,0.f,0.f};
            if (g*4 < TP) v = rin4[g];
            s4[i] = v;
        }
    }
    __syncthreads();
    if (a0 == 0) {   // designated writer per batch: rout row + recon
        if (!last) {
            const float4* rin4 = (const float4*)(rin + (size_t)b*TP);
            float4* rout4 = (float4*)(rout + (size_t)b*TP);
            for (int i = tid; i < TP/4; i += 256) {
                float4 v = rin4[i];
                int o = i*4 - pos;
                if (o > -4 && o < K) {
                    if (o+0 >= 0 && o+0 < K) v.x -= val * sm.dnsel[o+0];
                    if (o+1 >= 0 && o+1 < K) v.y -= val * sm.dnsel[o+1];
                    if (o+2 >= 0 && o+2 < K) v.z -= val * sm.dnsel[o+2];
                    if (o+3 >= 0 && o+3 < K) v.w -= val * sm.dnsel[o+3];
                }
                rout4[i] = v;
            }
        }
        recon[(size_t)b*TP + pos + tid] += val * sm.dnsel[tid];
    }
    if (last) return;

    // apply update delta in LDS (changed region [pos, pos+K) maps into the window)
    sm.rp[pos + tid - tbase] -= val * sm.dnsel[tid];
    __syncthreads();

    // recompute 1024 outputs [tbase, tbase+1024) for both atoms
    const float4* srp4 = (const float4*)sm.rp;
    const float4* dA4  = (const float4*)sm.dnA;
    const float4* dB4  = (const float4*)sm.dnB;
    float cA[4] = {0,0,0,0}, cB[4] = {0,0,0,0};
    float4 p = srp4[tid];
    #pragma unroll 4
    for (int kq = 0; kq < 64; kq++) {
        float4 dA = dA4[kq];
        float4 dB = dB4[kq];
        float4 pn = srp4[tid + kq + 1];
        TAP(cA[0], p.x,p.y,p.z,p.w, dA); TAP(cA[1], p.y,p.z,p.w,pn.x, dA);
        TAP(cA[2], p.z,p.w,pn.x,pn.y, dA); TAP(cA[3], p.w,pn.x,pn.y,pn.z, dA);
        TAP(cB[0], p.x,p.y,p.z,p.w, dB); TAP(cB[1], p.y,p.z,p.w,pn.x, dB);
        TAP(cB[2], p.z,p.w,pn.x,pn.y, dB); TAP(cB[3], p.w,pn.x,pn.y,pn.z, dB);
        p = pn;
    }
    int lt = tid * 4;
    float bvA = -INFINITY, bvB = -INFINITY;
    int biA = 0x7fffffff, biB = 0x7fffffff;
    #pragma unroll
    for (int j = 0; j < 4; j++) {
        int t = tbase + lt + j;
        if (t < TOUT) {
            if (cA[j] > bvA) { bvA = cA[j]; biA = aA*TOUT + t; }
            if (cB[j] > bvB) { bvB = cB[j]; biB = aB*TOUT + t; }
        }
    }
    wave_amax(bvA, biA); wave_amax(bvB, biB);
    if (lane == 0) { sm.wv[w] = bvA; sm.wi[w] = biA; sm.wv[8+w] = bvB; sm.wi[8+w] = biB; }
    __syncthreads();
    if (tid < 2) {         // atom A: chunk c_lo + tid <- waves (2*tid, 2*tid+1)
        float v0 = sm.wv[2*tid];   int i0 = sm.wi[2*tid];
        float v1 = sm.wv[2*tid+1]; int i1 = sm.wi[2*tid+1];
        if (v1 > v0 || (v1 == v0 && i1 < i0)) { v0 = v1; i0 = i1; }
        int chunk = c_lo + tid;
        if (chunk < NCHUNK) {
            segval[((size_t)b*A + aA)*NCP + chunk] = v0;
            segidx[((size_t)b*A + aA)*NCP + chunk] = i0;
        }
    } else if (tid >= 64 && tid < 66) {
        int c = tid - 64;
        float v0 = sm.wv[8+2*c];   int i0 = sm.wi[8+2*c];
        float v1 = sm.wv[8+2*c+1]; int i1 = sm.wi[8+2*c+1];
        if (v1 > v0 || (v1 == v0 && i1 < i0)) { v0 = v1; i0 = i1; }
        int chunk = c_lo + c;
        if (chunk < NCHUNK) {
            segval[((size_t)b*A + aB)*NCP + chunk] = v0;
            segidx[((size_t)b*A + aB)*NCP + chunk] = i0;
        }
    }
    __syncthreads();
    // refresh per-atom best over all 33 chunks
    if (w < 2) {
        int at = (w == 0) ? aA : aB;
        float bv = -INFINITY; int bi = 0x7fffffff;
        if (lane < NCHUNK) {
            bv = segval[((size_t)b*A + at)*NCP + lane];
            bi = segidx[((size_t)b*A + at)*NCP + lane];
        }
        wave_amax(bv, bi);
        if (lane == 0) { avn[b*A + at] = bv; ain[b*A + at] = bi; }
    }
}

// ================= cooperative single-kernel path =================
// launch_bounds(256,2): VGPR cap 256. (256,4) put the allocator in the 64-VGPR
// bucket and spilled 1 dword/thread/k-step in the conv loop -> 311 MB of
// scratch writes (measured R5). Grid is 512 blocks = 2/CU, so 2 waves/EU is
// exactly the occupancy needed.
__global__ void __launch_bounds__(256, 2)
k_coop(const float* __restrict__ x, const float* __restrict__ d, float* __restrict__ out,
       float* __restrict__ dn, float* __restrict__ rp0, float* __restrict__ rp1,
       float* __restrict__ recon, float* __restrict__ segval, int* __restrict__ segidx,
       float* __restrict__ abv0, int* __restrict__ abi0,
       float* __restrict__ abv1, int* __restrict__ abi1) {
    cg::grid_group grid = cg::this_grid();
    __shared__ Smem sm;
    const int bid = blockIdx.x, tid = threadIdx.x;
    const int a0 = bid & 127, b = bid >> 7;
    dev_norm(bid, tid, d, dn, sm);
    dev_init(bid, tid, x, rp0, recon);
    grid.sync();
    dev_conv(a0, b, tid, rp0, dn, segval, segidx, abv0, abi0, sm);
    grid.sync();
    const float* rin = rp0; float* rout = rp1;
    const float* avc = abv0; const int* aic = abi0;
    float* avn = abv1; int* ain = abi1;
    for (int it = 0; it < ITERS; it++) {
        dev_iter(a0, b, tid, it == ITERS-1, avc, aic, avn, ain,
                 rin, rout, recon, dn, segval, segidx, sm);
        { const float* t1 = rin; rin = rout; rout = (float*)t1; }
        { const float* t2 = avc; avc = avn; avn = (float*)t2; }
        { const int*   t3 = aic; aic = ain; ain = (int*)t3; }
        grid.sync();
    }
    for (int i = bid*256 + tid; i < B*T; i += NBLK*256) {
        int bb = i / T, t = i - bb*T;
        out[i] = recon[(size_t)bb*TP + PAD + t];
    }
}

// ================= non-cooperative fallback path =================
__global__ void __launch_bounds__(256) k_f_norm_init(const float* x, const float* d,
                                                     float* dn, float* rp0, float* recon) {
    __shared__ Smem sm;
    dev_norm(blockIdx.x, threadIdx.x, d, dn, sm);
    dev_init(blockIdx.x, threadIdx.x, x, rp0, recon);
}
__global__ void __launch_bounds__(256, 2) k_f_conv(const float* rp, const float* dn,
                                                   float* segval, int* segidx,
                                                   float* abv, int* abi) {
    __shared__ Smem sm;
    dev_conv(blockIdx.x & 127, blockIdx.x >> 7, threadIdx.x, rp, dn, segval, segidx, abv, abi, sm);
}
__global__ void __launch_bounds__(256, 2) k_f_iter(int last,
                                                   const float* avc, const int* aic,
                                                   float* avn, int* ain,
                                                   const float* rin, float* rout,
                                                   float* recon, const float* dn,
                                                   float* segval, int* segidx) {
    __shared__ Smem sm;
    dev_iter(blockIdx.x & 127, blockIdx.x >> 7, threadIdx.x, last,
             avc, aic, avn, ain, rin, rout, recon, dn, segval, segidx, sm);
}
__global__ void k_f_out(const float* recon, float* out) {
    int i = blockIdx.x * blockDim.x + threadIdx.x;
    if (i >= B*T) return;
    int b = i / T, t = i - b*T;
    out[i] = recon[(size_t)b*TP + PAD + t];
}

extern "C" void kernel_launch(void* const* d_in, const int* in_sizes, int n_in,
                              void* d_out, int out_size, void* d_ws, size_t ws_size,
                              hipStream_t stream) {
    const float* x = (const float*)d_in[0];
    const float* d = (const float*)d_in[1];
    float* out = (float*)d_out;

    float* ws     = (float*)d_ws;
    float* dn     = ws;                                   // A*K
    float* rp0    = dn  + (size_t)A*K;                    // B*TP
    float* rp1    = rp0 + (size_t)B*TP;                   // B*TP
    float* recon  = rp1 + (size_t)B*TP;                   // B*TP
    float* segval = recon + (size_t)B*TP;                 // B*A*NCP
    int*   segidx = (int*)(segval + (size_t)B*A*NCP);     // B*A*NCP
    float* abv0   = (float*)(segidx + (size_t)B*A*NCP);   // B*A
    float* abv1   = abv0 + (size_t)B*A;                   // B*A
    int*   abi0   = (int*)(abv1 + (size_t)B*A);           // B*A
    int*   abi1   = abi0 + (size_t)B*A;                   // B*A

    // deterministic cooperative-launch feasibility check (host queries only)
    int nb = 0, ncu = 0;
    hipError_t e1 = hipOccupancyMaxActiveBlocksPerMultiprocessor(&nb, (const void*)k_coop, 256, 0);
    hipError_t e2 = hipDeviceGetAttribute(&ncu, hipDeviceAttributeMultiprocessorCount, 0);
    bool coop = (e1 == hipSuccess && e2 == hipSuccess && nb > 0 && ncu > 0 &&
                 (long)nb * ncu >= NBLK);
    if (coop) {
        void* args[] = {(void*)&x, (void*)&d, (void*)&out, (void*)&dn,
                        (void*)&rp0, (void*)&rp1, (void*)&recon,
                        (void*)&segval, (void*)&segidx,
                        (void*)&abv0, (void*)&abi0, (void*)&abv1, (void*)&abi1};
        hipError_t e = hipLaunchCooperativeKernel((const void*)k_coop, dim3(NBLK), dim3(256),
                                                  args, 0, stream);
        if (e == hipSuccess) return;
    }
    // fallback: same device code, separate launches, double-buffered (race-free)
    k_f_norm_init<<<NBLK, 256, 0, stream>>>(x, d, dn, rp0, recon);
    k_f_conv<<<NBLK, 256, 0, stream>>>(rp0, dn, segval, segidx, abv0, abi0);
    float* rbuf[2] = {rp0, rp1};
    float* av[2]   = {abv0, abv1};
    int*   ai[2]   = {abi0, abi1};
    for (int it = 0; it < ITERS; it++) {
        k_f_iter<<<NBLK, 256, 0, stream>>>(it == ITERS-1 ? 1 : 0,
                                           av[it & 1], ai[it & 1],
                                           av[(it + 1) & 1], ai[(it + 1) & 1],
                                           rbuf[it & 1], rbuf[(it + 1) & 1],
                                           recon, dn, segval, segidx);
    }
    k_f_out<<<(B*T + 255)/256, 256, 0, stream>>>(recon, out);
}

// Round 7
// 581.968 us; speedup vs baseline: 2.6972x; 1.0042x over previous
//
#include <hip/hip_runtime.h>
#include <hip/hip_cooperative_groups.h>
#include <math.h>

namespace cg = cooperative_groups;

#define B    4
#define T    16384
#define A    256
#define K    256
#define PAD  128
#define TP   (T + 2*PAD)      // 16640
#define TOUT (TP - K + 1)     // 16385
#define ITERS 16
#define CHUNK 512
#define NCHUNK 33
#define NCP  36               // padded per-atom chunk stride
#define TILE 2048
#define NTILE 9
#define NBLK 512              // block owns atoms (2*a0, 2*a0+1) of batch b

struct Smem {
    float rp[TILE + K + 16];  // 2320 floats
    float dnA[K];
    float dnB[K];
    float dnsel[K];
    float wv[16]; int wi[16];
    float fv; int fi;
};

#define TAP(acc, s0,s1,s2,s3, dq) { acc = fmaf(s0,(dq).x,acc); acc = fmaf(s1,(dq).y,acc); \
                                    acc = fmaf(s2,(dq).z,acc); acc = fmaf(s3,(dq).w,acc); }

__device__ __forceinline__ void wave_amax(float& bv, int& bi) {
    #pragma unroll
    for (int off = 32; off; off >>= 1) {
        float ov = __shfl_down(bv, off);
        int   oi = __shfl_down(bi, off);
        if (ov > bv || (ov == bv && oi < bi)) { bv = ov; bi = oi; }
    }
}

// Lightweight grid barrier: monotonic counter, release-add + acquire-spin.
// Safe only under cooperative launch (all blocks co-resident).
__device__ __forceinline__ void gbar(unsigned* c, unsigned target) {
    __syncthreads();
    if (threadIdx.x == 0) {
        __hip_atomic_fetch_add(c, 1u, __ATOMIC_RELEASE, __HIP_MEMORY_SCOPE_AGENT);
        while (__hip_atomic_load(c, __ATOMIC_ACQUIRE, __HIP_MEMORY_SCOPE_AGENT) < target)
            __builtin_amdgcn_s_sleep(2);
    }
    __syncthreads();
}

// ---------- phase 0: normalize (blocks 0..127 handle atoms 2a0,2a0+1) + init ----------
__device__ __forceinline__ void dev_norm(int bid, int tid, const float* __restrict__ d,
                                         float* __restrict__ dn, Smem& sm) {
    if (bid < 128) {
        int lane = tid & 63, w = tid >> 6;
        #pragma unroll
        for (int s = 0; s < 2; s++) {
            int atom = (bid & 127)*2 + s;
            float v = d[atom*K + tid];
            float sq = v*v;
            #pragma unroll
            for (int off = 32; off; off >>= 1) sq += __shfl_down(sq, off);
            if (lane == 0) sm.wv[w] = sq;
            __syncthreads();
            float norm = sqrtf(sm.wv[0] + sm.wv[1] + sm.wv[2] + sm.wv[3]) + 1e-12f;
            dn[atom*K + tid] = v / norm;
            __syncthreads();
        }
    }
}

__device__ __forceinline__ void dev_init(int bid, int tid, const float* __restrict__ x,
                                         float* __restrict__ rp, float* __restrict__ recon) {
    for (int i = bid*256 + tid; i < B*TP; i += NBLK*256) {
        int bb = i / TP, t = i - bb*TP;
        float v = (t >= PAD && t < PAD + T) ? x[bb*T + (t - PAD)] : 0.f;
        rp[i] = v;
        recon[i] = 0.f;
    }
}

// ---------- phase 1: full conv for 2 atoms, chunk maxima -> segval, atom best -> abv ----
__device__ void dev_conv(int a0, int b, int tid, const float* __restrict__ rp,
                         const float* __restrict__ dn,
                         float* __restrict__ segval, int* __restrict__ segidx,
                         float* __restrict__ abv, int* __restrict__ abi, Smem& sm) {
    const int aA = a0*2, aB = a0*2 + 1;
    const int lane = tid & 63, w = tid >> 6;
    sm.dnA[tid] = dn[aA*K + tid];
    sm.dnB[tid] = dn[aB*K + tid];
    const float4* rp4 = (const float4*)(rp + (size_t)b*TP);

    for (int tile = 0; tile < NTILE; tile++) {
        int t0 = tile * TILE;
        __syncthreads();
        float4* s4 = (float4*)sm.rp;
        for (int i = tid; i < 580; i += 256) {
            int g = t0/4 + i;
            float4 v = {0.f,0.f,0.f,0.f};
            if (g*4 < TP) v = rp4[g];
            s4[i] = v;
        }
        __syncthreads();
        const float4* srp4 = (const float4*)sm.rp;
        const float4* dA4  = (const float4*)sm.dnA;
        const float4* dB4  = (const float4*)sm.dnB;
        float accA0[4] = {0,0,0,0}, accA1[4] = {0,0,0,0};
        float accB0[4] = {0,0,0,0}, accB1[4] = {0,0,0,0};
        float4 p = srp4[tid];
        float4 q = srp4[tid + 256];
        #pragma unroll 4
        for (int kq = 0; kq < 64; kq++) {
            float4 dA = dA4[kq];
            float4 dB = dB4[kq];
            float4 pn = srp4[tid + kq + 1];
            float4 qn = srp4[tid + 256 + kq + 1];
            TAP(accA0[0], p.x,p.y,p.z,p.w, dA); TAP(accA0[1], p.y,p.z,p.w,pn.x, dA);
            TAP(accA0[2], p.z,p.w,pn.x,pn.y, dA); TAP(accA0[3], p.w,pn.x,pn.y,pn.z, dA);
            TAP(accB0[0], p.x,p.y,p.z,p.w, dB); TAP(accB0[1], p.y,p.z,p.w,pn.x, dB);
            TAP(accB0[2], p.z,p.w,pn.x,pn.y, dB); TAP(accB0[3], p.w,pn.x,pn.y,pn.z, dB);
            TAP(accA1[0], q.x,q.y,q.z,q.w, dA); TAP(accA1[1], q.y,q.z,q.w,qn.x, dA);
            TAP(accA1[2], q.z,q.w,qn.x,qn.y, dA); TAP(accA1[3], q.w,qn.x,qn.y,qn.z, dA);
            TAP(accB1[0], q.x,q.y,q.z,q.w, dB); TAP(accB1[1], q.y,q.z,q.w,qn.x, dB);
            TAP(accB1[2], q.z,q.w,qn.x,qn.y, dB); TAP(accB1[3], q.w,qn.x,qn.y,qn.z, dB);
            p = pn; q = qn;
        }
        int lt = tid * 4;
        float bvA0 = -INFINITY, bvA1 = -INFINITY, bvB0 = -INFINITY, bvB1 = -INFINITY;
        int biA0 = 0x7fffffff, biA1 = 0x7fffffff, biB0 = 0x7fffffff, biB1 = 0x7fffffff;
        #pragma unroll
        for (int j = 0; j < 4; j++) {
            int t = t0 + lt + j;
            if (t < TOUT) {
                if (accA0[j] > bvA0) { bvA0 = accA0[j]; biA0 = aA*TOUT + t; }
                if (accB0[j] > bvB0) { bvB0 = accB0[j]; biB0 = aB*TOUT + t; }
            }
            int t1 = t0 + 1024 + lt + j;
            if (t1 < TOUT) {
                if (accA1[j] > bvA1) { bvA1 = accA1[j]; biA1 = aA*TOUT + t1; }
                if (accB1[j] > bvB1) { bvB1 = accB1[j]; biB1 = aB*TOUT + t1; }
            }
        }
        wave_amax(bvA0, biA0); wave_amax(bvA1, biA1);
        wave_amax(bvB0, biB0); wave_amax(bvB1, biB1);
        if (lane == 0) {
            sm.wv[w]    = bvA0; sm.wi[w]    = biA0;
            sm.wv[4+w]  = bvA1; sm.wi[4+w]  = biA1;
            sm.wv[8+w]  = bvB0; sm.wi[8+w]  = biB0;
            sm.wv[12+w] = bvB1; sm.wi[12+w] = biB1;
        }
        __syncthreads();
        // chunk c (0..3 in tile): partial pair (2c, 2c+1); atom B at +8
        if (tid < 4) {
            float v0 = sm.wv[2*tid];   int i0 = sm.wi[2*tid];
            float v1 = sm.wv[2*tid+1]; int i1 = sm.wi[2*tid+1];
            if (v1 > v0 || (v1 == v0 && i1 < i0)) { v0 = v1; i0 = i1; }
            int chunk = tile*4 + tid;
            if (chunk < NCHUNK) {
                segval[((size_t)b*A + aA)*NCP + chunk] = v0;
                segidx[((size_t)b*A + aA)*NCP + chunk] = i0;
            }
        } else if (tid >= 64 && tid < 68) {
            int c = tid - 64;
            float v0 = sm.wv[8+2*c];   int i0 = sm.wi[8+2*c];
            float v1 = sm.wv[8+2*c+1]; int i1 = sm.wi[8+2*c+1];
            if (v1 > v0 || (v1 == v0 && i1 < i0)) { v0 = v1; i0 = i1; }
            int chunk = tile*4 + c;
            if (chunk < NCHUNK) {
                segval[((size_t)b*A + aB)*NCP + chunk] = v0;
                segidx[((size_t)b*A + aB)*NCP + chunk] = i0;
            }
        }
    }
    __syncthreads();
    // per-atom best over 33 chunks (wave0 -> atom A, wave1 -> atom B)
    if (w < 2) {
        int atom = (w == 0) ? aA : aB;
        float bv = -INFINITY; int bi = 0x7fffffff;
        if (lane < NCHUNK) {
            bv = segval[((size_t)b*A + atom)*NCP + lane];
            bi = segidx[((size_t)b*A + atom)*NCP + lane];
        }
        wave_amax(bv, bi);
        if (lane == 0) { abv[b*A + atom] = bv; abi[b*A + atom] = bi; }
    }
}

// ---------- one matching-pursuit iteration ----------
__device__ void dev_iter(int a0, int b, int tid, int last,
                         const float* __restrict__ avc, const int* __restrict__ aic,
                         float* __restrict__ avn, int* __restrict__ ain,
                         const float* __restrict__ rin, float* __restrict__ rout,
                         float* __restrict__ recon, const float* __restrict__ dn,
                         float* __restrict__ segval, int* __restrict__ segidx, Smem& sm) {
    const int aA = a0*2, aB = a0*2 + 1;
    const int lane = tid & 63, w = tid >> 6;
    sm.dnA[tid] = dn[aA*K + tid];
    sm.dnB[tid] = dn[aB*K + tid];
    // pick (redundant, deterministic across blocks of batch b)
    {
        float bv = avc[b*A + tid]; int bi = aic[b*A + tid];
        wave_amax(bv, bi);
        if (lane == 0) { sm.wv[w] = bv; sm.wi[w] = bi; }
        __syncthreads();
        if (tid == 0) {
            bv = sm.wv[0]; bi = sm.wi[0];
            for (int j = 1; j < 4; j++)
                if (sm.wv[j] > bv || (sm.wv[j] == bv && sm.wi[j] < bi)) { bv = sm.wv[j]; bi = sm.wi[j]; }
            sm.fv = bv; sm.fi = bi;
        }
        __syncthreads();
    }
    float val = sm.fv; int idx = sm.fi;
    int atom = idx / TOUT, pos = idx - atom*TOUT;
    sm.dnsel[tid] = dn[atom*K + tid];

    int lo = pos - (K-1); if (lo < 0) lo = 0;
    int c_lo = lo >> 9;
    int tbase = c_lo * CHUNK;

    if (!last) {   // stage window [tbase, tbase+1296)
        const float4* rin4 = (const float4*)(rin + (size_t)b*TP);
        float4* s4 = (float4*)sm.rp;
        for (int i = tid; i < 324; i += 256) {
            int g = tbase/4 + i;
            float4 v = {0.f,0.f,0.f,0.f};
            if (g*4 < TP) v = rin4[g];
            s4[i] = v;
        }
    }
    __syncthreads();
    if (a0 == 0) {   // designated writer per batch: rout row + recon
        if (!last) {
            const float4* rin4 = (const float4*)(rin + (size_t)b*TP);
            float4* rout4 = (float4*)(rout + (size_t)b*TP);
            for (int i = tid; i < TP/4; i += 256) {
                float4 v = rin4[i];
                int o = i*4 - pos;
                if (o > -4 && o < K) {
                    if (o+0 >= 0 && o+0 < K) v.x -= val * sm.dnsel[o+0];
                    if (o+1 >= 0 && o+1 < K) v.y -= val * sm.dnsel[o+1];
                    if (o+2 >= 0 && o+2 < K) v.z -= val * sm.dnsel[o+2];
                    if (o+3 >= 0 && o+3 < K) v.w -= val * sm.dnsel[o+3];
                }
                rout4[i] = v;
            }
        }
        recon[(size_t)b*TP + pos + tid] += val * sm.dnsel[tid];
    }
    if (last) return;

    // apply update delta in LDS (changed region [pos, pos+K) maps into the window)
    sm.rp[pos + tid - tbase] -= val * sm.dnsel[tid];
    __syncthreads();

    // recompute 1024 outputs [tbase, tbase+1024) for both atoms
    const float4* srp4 = (const float4*)sm.rp;
    const float4* dA4  = (const float4*)sm.dnA;
    const float4* dB4  = (const float4*)sm.dnB;
    float cA[4] = {0,0,0,0}, cB[4] = {0,0,0,0};
    float4 p = srp4[tid];
    #pragma unroll 4
    for (int kq = 0; kq < 64; kq++) {
        float4 dA = dA4[kq];
        float4 dB = dB4[kq];
        float4 pn = srp4[tid + kq + 1];
        TAP(cA[0], p.x,p.y,p.z,p.w, dA); TAP(cA[1], p.y,p.z,p.w,pn.x, dA);
        TAP(cA[2], p.z,p.w,pn.x,pn.y, dA); TAP(cA[3], p.w,pn.x,pn.y,pn.z, dA);
        TAP(cB[0], p.x,p.y,p.z,p.w, dB); TAP(cB[1], p.y,p.z,p.w,pn.x, dB);
        TAP(cB[2], p.z,p.w,pn.x,pn.y, dB); TAP(cB[3], p.w,pn.x,pn.y,pn.z, dB);
        p = pn;
    }
    int lt = tid * 4;
    float bvA = -INFINITY, bvB = -INFINITY;
    int biA = 0x7fffffff, biB = 0x7fffffff;
    #pragma unroll
    for (int j = 0; j < 4; j++) {
        int t = tbase + lt + j;
        if (t < TOUT) {
            if (cA[j] > bvA) { bvA = cA[j]; biA = aA*TOUT + t; }
            if (cB[j] > bvB) { bvB = cB[j]; biB = aB*TOUT + t; }
        }
    }
    wave_amax(bvA, biA); wave_amax(bvB, biB);
    if (lane == 0) { sm.wv[w] = bvA; sm.wi[w] = biA; sm.wv[8+w] = bvB; sm.wi[8+w] = biB; }
    __syncthreads();
    if (tid < 2) {         // atom A: chunk c_lo + tid <- waves (2*tid, 2*tid+1)
        float v0 = sm.wv[2*tid];   int i0 = sm.wi[2*tid];
        float v1 = sm.wv[2*tid+1]; int i1 = sm.wi[2*tid+1];
        if (v1 > v0 || (v1 == v0 && i1 < i0)) { v0 = v1; i0 = i1; }
        int chunk = c_lo + tid;
        if (chunk < NCHUNK) {
            segval[((size_t)b*A + aA)*NCP + chunk] = v0;
            segidx[((size_t)b*A + aA)*NCP + chunk] = i0;
        }
    } else if (tid >= 64 && tid < 66) {
        int c = tid - 64;
        float v0 = sm.wv[8+2*c];   int i0 = sm.wi[8+2*c];
        float v1 = sm.wv[8+2*c+1]; int i1 = sm.wi[8+2*c+1];
        if (v1 > v0 || (v1 == v0 && i1 < i0)) { v0 = v1; i0 = i1; }
        int chunk = c_lo + c;
        if (chunk < NCHUNK) {
            segval[((size_t)b*A + aB)*NCP + chunk] = v0;
            segidx[((size_t)b*A + aB)*NCP + chunk] = i0;
        }
    }
    __syncthreads();
    // refresh per-atom best over all 33 chunks
    if (w < 2) {
        int at = (w == 0) ? aA : aB;
        float bv = -INFINITY; int bi = 0x7fffffff;
        if (lane < NCHUNK) {
            bv = segval[((size_t)b*A + at)*NCP + lane];
            bi = segidx[((size_t)b*A + at)*NCP + lane];
        }
        wave_amax(bv, bi);
        if (lane == 0) { avn[b*A + at] = bv; ain[b*A + at] = bi; }
    }
}

// ================= cooperative single-kernel path =================
__global__ void __launch_bounds__(256, 2)
k_coop(const float* __restrict__ x, const float* __restrict__ d, float* __restrict__ out,
       float* __restrict__ dn, float* __restrict__ rp0, float* __restrict__ rp1,
       float* __restrict__ recon, float* __restrict__ segval, int* __restrict__ segidx,
       float* __restrict__ abv0, int* __restrict__ abi0,
       float* __restrict__ abv1, int* __restrict__ abi1, unsigned* __restrict__ bar) {
    __shared__ Smem sm;
    const int bid = blockIdx.x, tid = threadIdx.x;
    const int a0 = bid & 127, b = bid >> 7;
    unsigned gen = 0;
    dev_norm(bid, tid, d, dn, sm);
    dev_init(bid, tid, x, rp0, recon);
    gen++; gbar(bar, gen*NBLK);
    dev_conv(a0, b, tid, rp0, dn, segval, segidx, abv0, abi0, sm);
    gen++; gbar(bar, gen*NBLK);
    const float* rin = rp0; float* rout = rp1;
    const float* avc = abv0; const int* aic = abi0;
    float* avn = abv1; int* ain = abi1;
    for (int it = 0; it < ITERS; it++) {
        dev_iter(a0, b, tid, it == ITERS-1, avc, aic, avn, ain,
                 rin, rout, recon, dn, segval, segidx, sm);
        { const float* t1 = rin; rin = rout; rout = (float*)t1; }
        { const float* t2 = avc; avc = avn; avn = (float*)t2; }
        { const int*   t3 = aic; aic = ain; ain = (int*)t3; }
        gen++; gbar(bar, gen*NBLK);
    }
    for (int i = bid*256 + tid; i < B*T; i += NBLK*256) {
        int bb = i / T, t = i - bb*T;
        out[i] = recon[(size_t)bb*TP + PAD + t];
    }
}

// ================= non-cooperative fallback path =================
__global__ void __launch_bounds__(256) k_f_norm_init(const float* x, const float* d,
                                                     float* dn, float* rp0, float* recon) {
    __shared__ Smem sm;
    dev_norm(blockIdx.x, threadIdx.x, d, dn, sm);
    dev_init(blockIdx.x, threadIdx.x, x, rp0, recon);
}
__global__ void __launch_bounds__(256, 2) k_f_conv(const float* rp, const float* dn,
                                                   float* segval, int* segidx,
                                                   float* abv, int* abi) {
    __shared__ Smem sm;
    dev_conv(blockIdx.x & 127, blockIdx.x >> 7, threadIdx.x, rp, dn, segval, segidx, abv, abi, sm);
}
__global__ void __launch_bounds__(256, 2) k_f_iter(int last,
                                                   const float* avc, const int* aic,
                                                   float* avn, int* ain,
                                                   const float* rin, float* rout,
                                                   float* recon, const float* dn,
                                                   float* segval, int* segidx) {
    __shared__ Smem sm;
    dev_iter(blockIdx.x & 127, blockIdx.x >> 7, threadIdx.x, last,
             avc, aic, avn, ain, rin, rout, recon, dn, segval, segidx, sm);
}
__global__ void k_f_out(const float* recon, float* out) {
    int i = blockIdx.x * blockDim.x + threadIdx.x;
    if (i >= B*T) return;
    int b = i / T, t = i - b*T;
    out[i] = recon[(size_t)b*TP + PAD + t];
}

extern "C" void kernel_launch(void* const* d_in, const int* in_sizes, int n_in,
                              void* d_out, int out_size, void* d_ws, size_t ws_size,
                              hipStream_t stream) {
    const float* x = (const float*)d_in[0];
    const float* d = (const float*)d_in[1];
    float* out = (float*)d_out;

    float* ws     = (float*)d_ws;
    float* dn     = ws;                                   // A*K
    float* rp0    = dn  + (size_t)A*K;                    // B*TP
    float* rp1    = rp0 + (size_t)B*TP;                   // B*TP
    float* recon  = rp1 + (size_t)B*TP;                   // B*TP
    float* segval = recon + (size_t)B*TP;                 // B*A*NCP
    int*   segidx = (int*)(segval + (size_t)B*A*NCP);     // B*A*NCP
    float* abv0   = (float*)(segidx + (size_t)B*A*NCP);   // B*A
    float* abv1   = abv0 + (size_t)B*A;                   // B*A
    int*   abi0   = (int*)(abv1 + (size_t)B*A);           // B*A
    int*   abi1   = abi0 + (size_t)B*A;                   // B*A
    unsigned* bar = (unsigned*)(abi1 + (size_t)B*A);      // barrier counter

    // deterministic cooperative-launch feasibility check (host queries only)
    int nb = 0, ncu = 0;
    hipError_t e1 = hipOccupancyMaxActiveBlocksPerMultiprocessor(&nb, (const void*)k_coop, 256, 0);
    hipError_t e2 = hipDeviceGetAttribute(&ncu, hipDeviceAttributeMultiprocessorCount, 0);
    bool coop = (e1 == hipSuccess && e2 == hipSuccess && nb > 0 && ncu > 0 &&
                 (long)nb * ncu >= NBLK);
    if (coop) {
        hipMemsetAsync(bar, 0, 64, stream);   // zero barrier counter (graph-safe)
        void* args[] = {(void*)&x, (void*)&d, (void*)&out, (void*)&dn,
                        (void*)&rp0, (void*)&rp1, (void*)&recon,
                        (void*)&segval, (void*)&segidx,
                        (void*)&abv0, (void*)&abi0, (void*)&abv1, (void*)&abi1,
                        (void*)&bar};
        hipError_t e = hipLaunchCooperativeKernel((const void*)k_coop, dim3(NBLK), dim3(256),
                                                  args, 0, stream);
        if (e == hipSuccess) return;
    }
    // fallback: same device code, separate launches, double-buffered (race-free)
    k_f_norm_init<<<NBLK, 256, 0, stream>>>(x, d, dn, rp0, recon);
    k_f_conv<<<NBLK, 256, 0, stream>>>(rp0, dn, segval, segidx, abv0, abi0);
    float* rbuf[2] = {rp0, rp1};
    float* av[2]   = {abv0, abv1};
    int*   ai[2]   = {abi0, abi1};
    for (int it = 0; it < ITERS; it++) {
        k_f_iter<<<NBLK, 256, 0, stream>>>(it == ITERS-1 ? 1 : 0,
                                           av[it & 1], ai[it & 1],
                                           av[(it + 1) & 1], ai[(it + 1) & 1],
                                           rbuf[it & 1], rbuf[(it + 1) & 1],
                                           recon, dn, segval, segidx);
    }
    k_f_out<<<(B*T + 255)/256, 256, 0, stream>>>(recon, out);
}

// Round 8
// 547.331 us; speedup vs baseline: 2.8678x; 1.0633x over previous
//
#include <hip/hip_runtime.h>
#include <hip/hip_cooperative_groups.h>
#include <math.h>

namespace cg = cooperative_groups;

#define B    4
#define T    16384
#define A    256
#define K    256
#define PAD  128
#define TP   (T + 2*PAD)      // 16640
#define TOUT (TP - K + 1)     // 16385
#define ITERS 16
#define CHUNK 512
#define NCHUNK 33
#define NCP  36               // padded per-atom chunk stride
#define TILE 2048
#define NTILE 9
#define NBLK 512              // block owns atoms (2*a0, 2*a0+1) of batch b

struct Smem {
    float rp[TILE + K + 16];  // 2320 floats
    float dnA[K];
    float dnB[K];
    float dnsel[K];
    float wv[16]; int wi[16];
    float fv; int fi;
};

#define TAP(acc, s0,s1,s2,s3, dq) { acc = fmaf(s0,(dq).x,acc); acc = fmaf(s1,(dq).y,acc); \
                                    acc = fmaf(s2,(dq).z,acc); acc = fmaf(s3,(dq).w,acc); }

__device__ __forceinline__ void wave_amax(float& bv, int& bi) {
    #pragma unroll
    for (int off = 32; off; off >>= 1) {
        float ov = __shfl_down(bv, off);
        int   oi = __shfl_down(bi, off);
        if (ov > bv || (ov == bv && oi < bi)) { bv = ov; bi = oi; }
    }
}

// Lightweight grid barrier: monotonic counter, release-add + acquire-spin.
// Safe only under cooperative launch (all blocks co-resident).
__device__ __forceinline__ void gbar(unsigned* c, unsigned target) {
    __syncthreads();
    if (threadIdx.x == 0) {
        __hip_atomic_fetch_add(c, 1u, __ATOMIC_RELEASE, __HIP_MEMORY_SCOPE_AGENT);
        while (__hip_atomic_load(c, __ATOMIC_ACQUIRE, __HIP_MEMORY_SCOPE_AGENT) < target)
            __builtin_amdgcn_s_sleep(2);
    }
    __syncthreads();
}

// ---------- phase 0: normalize (blocks 0..127 handle atoms 2a0,2a0+1) + init ----------
__device__ __forceinline__ void dev_norm(int bid, int tid, const float* __restrict__ d,
                                         float* __restrict__ dn, Smem& sm) {
    if (bid < 128) {
        int lane = tid & 63, w = tid >> 6;
        #pragma unroll
        for (int s = 0; s < 2; s++) {
            int atom = (bid & 127)*2 + s;
            float v = d[atom*K + tid];
            float sq = v*v;
            #pragma unroll
            for (int off = 32; off; off >>= 1) sq += __shfl_down(sq, off);
            if (lane == 0) sm.wv[w] = sq;
            __syncthreads();
            float norm = sqrtf(sm.wv[0] + sm.wv[1] + sm.wv[2] + sm.wv[3]) + 1e-12f;
            dn[atom*K + tid] = v / norm;
            __syncthreads();
        }
    }
}

__device__ __forceinline__ void dev_init(int bid, int tid, const float* __restrict__ x,
                                         float* __restrict__ rp, float* __restrict__ recon) {
    for (int i = bid*256 + tid; i < B*TP; i += NBLK*256) {
        int bb = i / TP, t = i - bb*TP;
        float v = (t >= PAD && t < PAD + T) ? x[bb*T + (t - PAD)] : 0.f;
        rp[i] = v;
        recon[i] = 0.f;
    }
}

// ---------- phase 1: full conv for 2 atoms, chunk maxima -> segval, atom best -> abv ----
__device__ void dev_conv(int a0, int b, int tid, const float* __restrict__ rp,
                         const float* __restrict__ dn,
                         float* __restrict__ segval, int* __restrict__ segidx,
                         float* __restrict__ abv, int* __restrict__ abi, Smem& sm) {
    const int aA = a0*2, aB = a0*2 + 1;
    const int lane = tid & 63, w = tid >> 6;
    sm.dnA[tid] = dn[aA*K + tid];
    sm.dnB[tid] = dn[aB*K + tid];
    const float4* rp4 = (const float4*)(rp + (size_t)b*TP);

    for (int tile = 0; tile < NTILE; tile++) {
        int t0 = tile * TILE;
        __syncthreads();
        float4* s4 = (float4*)sm.rp;
        for (int i = tid; i < 580; i += 256) {
            int g = t0/4 + i;
            float4 v = {0.f,0.f,0.f,0.f};
            if (g*4 < TP) v = rp4[g];
            s4[i] = v;
        }
        __syncthreads();
        const float4* srp4 = (const float4*)sm.rp;
        const float4* dA4  = (const float4*)sm.dnA;
        const float4* dB4  = (const float4*)sm.dnB;
        float accA0[4] = {0,0,0,0}, accA1[4] = {0,0,0,0};
        float accB0[4] = {0,0,0,0}, accB1[4] = {0,0,0,0};
        float4 p = srp4[tid];
        float4 q = srp4[tid + 256];
        #pragma unroll 4
        for (int kq = 0; kq < 64; kq++) {
            float4 dA = dA4[kq];
            float4 dB = dB4[kq];
            float4 pn = srp4[tid + kq + 1];
            float4 qn = srp4[tid + 256 + kq + 1];
            TAP(accA0[0], p.x,p.y,p.z,p.w, dA); TAP(accA0[1], p.y,p.z,p.w,pn.x, dA);
            TAP(accA0[2], p.z,p.w,pn.x,pn.y, dA); TAP(accA0[3], p.w,pn.x,pn.y,pn.z, dA);
            TAP(accB0[0], p.x,p.y,p.z,p.w, dB); TAP(accB0[1], p.y,p.z,p.w,pn.x, dB);
            TAP(accB0[2], p.z,p.w,pn.x,pn.y, dB); TAP(accB0[3], p.w,pn.x,pn.y,pn.z, dB);
            TAP(accA1[0], q.x,q.y,q.z,q.w, dA); TAP(accA1[1], q.y,q.z,q.w,qn.x, dA);
            TAP(accA1[2], q.z,q.w,qn.x,qn.y, dA); TAP(accA1[3], q.w,qn.x,qn.y,qn.z, dA);
            TAP(accB1[0], q.x,q.y,q.z,q.w, dB); TAP(accB1[1], q.y,q.z,q.w,qn.x, dB);
            TAP(accB1[2], q.z,q.w,qn.x,qn.y, dB); TAP(accB1[3], q.w,qn.x,qn.y,qn.z, dB);
            p = pn; q = qn;
        }
        int lt = tid * 4;
        float bvA0 = -INFINITY, bvA1 = -INFINITY, bvB0 = -INFINITY, bvB1 = -INFINITY;
        int biA0 = 0x7fffffff, biA1 = 0x7fffffff, biB0 = 0x7fffffff, biB1 = 0x7fffffff;
        #pragma unroll
        for (int j = 0; j < 4; j++) {
            int t = t0 + lt + j;
            if (t < TOUT) {
                if (accA0[j] > bvA0) { bvA0 = accA0[j]; biA0 = aA*TOUT + t; }
                if (accB0[j] > bvB0) { bvB0 = accB0[j]; biB0 = aB*TOUT + t; }
            }
            int t1 = t0 + 1024 + lt + j;
            if (t1 < TOUT) {
                if (accA1[j] > bvA1) { bvA1 = accA1[j]; biA1 = aA*TOUT + t1; }
                if (accB1[j] > bvB1) { bvB1 = accB1[j]; biB1 = aB*TOUT + t1; }
            }
        }
        wave_amax(bvA0, biA0); wave_amax(bvA1, biA1);
        wave_amax(bvB0, biB0); wave_amax(bvB1, biB1);
        if (lane == 0) {
            sm.wv[w]    = bvA0; sm.wi[w]    = biA0;
            sm.wv[4+w]  = bvA1; sm.wi[4+w]  = biA1;
            sm.wv[8+w]  = bvB0; sm.wi[8+w]  = biB0;
            sm.wv[12+w] = bvB1; sm.wi[12+w] = biB1;
        }
        __syncthreads();
        // chunk c (0..3 in tile): partial pair (2c, 2c+1); atom B at +8
        if (tid < 4) {
            float v0 = sm.wv[2*tid];   int i0 = sm.wi[2*tid];
            float v1 = sm.wv[2*tid+1]; int i1 = sm.wi[2*tid+1];
            if (v1 > v0 || (v1 == v0 && i1 < i0)) { v0 = v1; i0 = i1; }
            int chunk = tile*4 + tid;
            if (chunk < NCHUNK) {
                segval[((size_t)b*A + aA)*NCP + chunk] = v0;
                segidx[((size_t)b*A + aA)*NCP + chunk] = i0;
            }
        } else if (tid >= 64 && tid < 68) {
            int c = tid - 64;
            float v0 = sm.wv[8+2*c];   int i0 = sm.wi[8+2*c];
            float v1 = sm.wv[8+2*c+1]; int i1 = sm.wi[8+2*c+1];
            if (v1 > v0 || (v1 == v0 && i1 < i0)) { v0 = v1; i0 = i1; }
            int chunk = tile*4 + c;
            if (chunk < NCHUNK) {
                segval[((size_t)b*A + aB)*NCP + chunk] = v0;
                segidx[((size_t)b*A + aB)*NCP + chunk] = i0;
            }
        }
    }
    __syncthreads();
    // per-atom best over 33 chunks (wave0 -> atom A, wave1 -> atom B)
    if (w < 2) {
        int atom = (w == 0) ? aA : aB;
        float bv = -INFINITY; int bi = 0x7fffffff;
        if (lane < NCHUNK) {
            bv = segval[((size_t)b*A + atom)*NCP + lane];
            bi = segidx[((size_t)b*A + atom)*NCP + lane];
        }
        wave_amax(bv, bi);
        if (lane == 0) { abv[b*A + atom] = bv; abi[b*A + atom] = bi; }
    }
}

// ---------- one matching-pursuit iteration ----------
__device__ void dev_iter(int a0, int b, int tid, int last,
                         const float* __restrict__ avc, const int* __restrict__ aic,
                         float* __restrict__ avn, int* __restrict__ ain,
                         const float* __restrict__ rin, float* __restrict__ rout,
                         float* __restrict__ recon, const float* __restrict__ dn,
                         float* __restrict__ segval, int* __restrict__ segidx, Smem& sm) {
    const int aA = a0*2, aB = a0*2 + 1;
    const int lane = tid & 63, w = tid >> 6;
    sm.dnA[tid] = dn[aA*K + tid];
    sm.dnB[tid] = dn[aB*K + tid];
    // pick (redundant, deterministic across blocks of same b)
    {
        float bv = avc[b*A + tid]; int bi = aic[b*A + tid];
        wave_amax(bv, bi);
        if (lane == 0) { sm.wv[w] = bv; sm.wi[w] = bi; }
        __syncthreads();
        if (tid == 0) {
            bv = sm.wv[0]; bi = sm.wi[0];
            for (int j = 1; j < 4; j++)
                if (sm.wv[j] > bv || (sm.wv[j] == bv && sm.wi[j] < bi)) { bv = sm.wv[j]; bi = sm.wi[j]; }
            sm.fv = bv; sm.fi = bi;
        }
        __syncthreads();
    }
    float val = sm.fv; int idx = sm.fi;
    int atom = idx / TOUT, pos = idx - atom*TOUT;
    sm.dnsel[tid] = dn[atom*K + tid];

    int lo = pos - (K-1); if (lo < 0) lo = 0;
    int c_lo = lo >> 9;
    int tbase = c_lo * CHUNK;

    if (!last) {   // stage window [tbase, tbase+1296)
        const float4* rin4 = (const float4*)(rin + (size_t)b*TP);
        float4* s4 = (float4*)sm.rp;
        for (int i = tid; i < 324; i += 256) {
            int g = tbase/4 + i;
            float4 v = {0.f,0.f,0.f,0.f};
            if (g*4 < TP) v = rin4[g];
            s4[i] = v;
        }
    }
    __syncthreads();
    // --- distributed rp row copy+update: quads 0..4159 spread over blocks a0=0..16
    // (R7 used a single designated block per batch -> ~15-25 us straggler per
    //  iteration gating the grid barrier; this is 1 float4 per thread.)
    if (!last) {
        const float4* rin4 = (const float4*)(rin + (size_t)b*TP);
        float4* rout4 = (float4*)(rout + (size_t)b*TP);
        int i = a0*256 + tid;
        if (i < TP/4) {
            float4 v = rin4[i];
            int o = i*4 - pos;
            if (o > -4 && o < K) {
                if (o+0 >= 0 && o+0 < K) v.x -= val * sm.dnsel[o+0];
                if (o+1 >= 0 && o+1 < K) v.y -= val * sm.dnsel[o+1];
                if (o+2 >= 0 && o+2 < K) v.z -= val * sm.dnsel[o+2];
                if (o+3 >= 0 && o+3 < K) v.w -= val * sm.dnsel[o+3];
            }
            rout4[i] = v;
        }
    }
    if (a0 == 0) {   // recon update: K floats, trivial
        recon[(size_t)b*TP + pos + tid] += val * sm.dnsel[tid];
    }
    if (last) return;

    // apply update delta in LDS (changed region [pos, pos+K) maps into the window)
    sm.rp[pos + tid - tbase] -= val * sm.dnsel[tid];
    __syncthreads();

    // recompute 1024 outputs [tbase, tbase+1024) for both atoms
    const float4* srp4 = (const float4*)sm.rp;
    const float4* dA4  = (const float4*)sm.dnA;
    const float4* dB4  = (const float4*)sm.dnB;
    float cA[4] = {0,0,0,0}, cB[4] = {0,0,0,0};
    float4 p = srp4[tid];
    #pragma unroll 4
    for (int kq = 0; kq < 64; kq++) {
        float4 dA = dA4[kq];
        float4 dB = dB4[kq];
        float4 pn = srp4[tid + kq + 1];
        TAP(cA[0], p.x,p.y,p.z,p.w, dA); TAP(cA[1], p.y,p.z,p.w,pn.x, dA);
        TAP(cA[2], p.z,p.w,pn.x,pn.y, dA); TAP(cA[3], p.w,pn.x,pn.y,pn.z, dA);
        TAP(cB[0], p.x,p.y,p.z,p.w, dB); TAP(cB[1], p.y,p.z,p.w,pn.x, dB);
        TAP(cB[2], p.z,p.w,pn.x,pn.y, dB); TAP(cB[3], p.w,pn.x,pn.y,pn.z, dB);
        p = pn;
    }
    int lt = tid * 4;
    float bvA = -INFINITY, bvB = -INFINITY;
    int biA = 0x7fffffff, biB = 0x7fffffff;
    #pragma unroll
    for (int j = 0; j < 4; j++) {
        int t = tbase + lt + j;
        if (t < TOUT) {
            if (cA[j] > bvA) { bvA = cA[j]; biA = aA*TOUT + t; }
            if (cB[j] > bvB) { bvB = cB[j]; biB = aB*TOUT + t; }
        }
    }
    wave_amax(bvA, biA); wave_amax(bvB, biB);
    if (lane == 0) { sm.wv[w] = bvA; sm.wi[w] = biA; sm.wv[8+w] = bvB; sm.wi[8+w] = biB; }
    __syncthreads();
    if (tid < 2) {         // atom A: chunk c_lo + tid <- waves (2*tid, 2*tid+1)
        float v0 = sm.wv[2*tid];   int i0 = sm.wi[2*tid];
        float v1 = sm.wv[2*tid+1]; int i1 = sm.wi[2*tid+1];
        if (v1 > v0 || (v1 == v0 && i1 < i0)) { v0 = v1; i0 = i1; }
        int chunk = c_lo + tid;
        if (chunk < NCHUNK) {
            segval[((size_t)b*A + aA)*NCP + chunk] = v0;
            segidx[((size_t)b*A + aA)*NCP + chunk] = i0;
        }
    } else if (tid >= 64 && tid < 66) {
        int c = tid - 64;
        float v0 = sm.wv[8+2*c];   int i0 = sm.wi[8+2*c];
        float v1 = sm.wv[8+2*c+1]; int i1 = sm.wi[8+2*c+1];
        if (v1 > v0 || (v1 == v0 && i1 < i0)) { v0 = v1; i0 = i1; }
        int chunk = c_lo + c;
        if (chunk < NCHUNK) {
            segval[((size_t)b*A + aB)*NCP + chunk] = v0;
            segidx[((size_t)b*A + aB)*NCP + chunk] = i0;
        }
    }
    __syncthreads();
    // refresh per-atom best over all 33 chunks
    if (w < 2) {
        int at = (w == 0) ? aA : aB;
        float bv = -INFINITY; int bi = 0x7fffffff;
        if (lane < NCHUNK) {
            bv = segval[((size_t)b*A + at)*NCP + lane];
            bi = segidx[((size_t)b*A + at)*NCP + lane];
        }
        wave_amax(bv, bi);
        if (lane == 0) { avn[b*A + at] = bv; ain[b*A + at] = bi; }
    }
}

// ================= cooperative single-kernel path =================
__global__ void __launch_bounds__(256, 2)
k_coop(const float* __restrict__ x, const float* __restrict__ d, float* __restrict__ out,
       float* __restrict__ dn, float* __restrict__ rp0, float* __restrict__ rp1,
       float* __restrict__ recon, float* __restrict__ segval, int* __restrict__ segidx,
       float* __restrict__ abv0, int* __restrict__ abi0,
       float* __restrict__ abv1, int* __restrict__ abi1, unsigned* __restrict__ bar) {
    __shared__ Smem sm;
    const int bid = blockIdx.x, tid = threadIdx.x;
    const int a0 = bid & 127, b = bid >> 7;
    unsigned gen = 0;
    dev_norm(bid, tid, d, dn, sm);
    dev_init(bid, tid, x, rp0, recon);
    gen++; gbar(bar, gen*NBLK);
    dev_conv(a0, b, tid, rp0, dn, segval, segidx, abv0, abi0, sm);
    gen++; gbar(bar, gen*NBLK);
    const float* rin = rp0; float* rout = rp1;
    const float* avc = abv0; const int* aic = abi0;
    float* avn = abv1; int* ain = abi1;
    for (int it = 0; it < ITERS; it++) {
        dev_iter(a0, b, tid, it == ITERS-1, avc, aic, avn, ain,
                 rin, rout, recon, dn, segval, segidx, sm);
        { const float* t1 = rin; rin = rout; rout = (float*)t1; }
        { const float* t2 = avc; avc = avn; avn = (float*)t2; }
        { const int*   t3 = aic; aic = ain; ain = (int*)t3; }
        gen++; gbar(bar, gen*NBLK);
    }
    for (int i = bid*256 + tid; i < B*T; i += NBLK*256) {
        int bb = i / T, t = i - bb*T;
        out[i] = recon[(size_t)bb*TP + PAD + t];
    }
}

// ================= non-cooperative fallback path =================
__global__ void __launch_bounds__(256) k_f_norm_init(const float* x, const float* d,
                                                     float* dn, float* rp0, float* recon) {
    __shared__ Smem sm;
    dev_norm(blockIdx.x, threadIdx.x, d, dn, sm);
    dev_init(blockIdx.x, threadIdx.x, x, rp0, recon);
}
__global__ void __launch_bounds__(256, 2) k_f_conv(const float* rp, const float* dn,
                                                   float* segval, int* segidx,
                                                   float* abv, int* abi) {
    __shared__ Smem sm;
    dev_conv(blockIdx.x & 127, blockIdx.x >> 7, threadIdx.x, rp, dn, segval, segidx, abv, abi, sm);
}
__global__ void __launch_bounds__(256, 2) k_f_iter(int last,
                                                   const float* avc, const int* aic,
                                                   float* avn, int* ain,
                                                   const float* rin, float* rout,
                                                   float* recon, const float* dn,
                                                   float* segval, int* segidx) {
    __shared__ Smem sm;
    dev_iter(blockIdx.x & 127, blockIdx.x >> 7, threadIdx.x, last,
             avc, aic, avn, ain, rin, rout, recon, dn, segval, segidx, sm);
}
__global__ void k_f_out(const float* recon, float* out) {
    int i = blockIdx.x * blockDim.x + threadIdx.x;
    if (i >= B*T) return;
    int b = i / T, t = i - b*T;
    out[i] = recon[(size_t)b*TP + PAD + t];
}

extern "C" void kernel_launch(void* const* d_in, const int* in_sizes, int n_in,
                              void* d_out, int out_size, void* d_ws, size_t ws_size,
                              hipStream_t stream) {
    const float* x = (const float*)d_in[0];
    const float* d = (const float*)d_in[1];
    float* out = (float*)d_out;

    float* ws     = (float*)d_ws;
    float* dn     = ws;                                   // A*K
    float* rp0    = dn  + (size_t)A*K;                    // B*TP
    float* rp1    = rp0 + (size_t)B*TP;                   // B*TP
    float* recon  = rp1 + (size_t)B*TP;                   // B*TP
    float* segval = recon + (size_t)B*TP;                 // B*A*NCP
    int*   segidx = (int*)(segval + (size_t)B*A*NCP);     // B*A*NCP
    float* abv0   = (float*)(segidx + (size_t)B*A*NCP);   // B*A
    float* abv1   = abv0 + (size_t)B*A;                   // B*A
    int*   abi0   = (int*)(abv1 + (size_t)B*A);           // B*A
    int*   abi1   = abi0 + (size_t)B*A;                   // B*A
    unsigned* bar = (unsigned*)(abi1 + (size_t)B*A);      // barrier counter

    // deterministic cooperative-launch feasibility check (host queries only)
    int nb = 0, ncu = 0;
    hipError_t e1 = hipOccupancyMaxActiveBlocksPerMultiprocessor(&nb, (const void*)k_coop, 256, 0);
    hipError_t e2 = hipDeviceGetAttribute(&ncu, hipDeviceAttributeMultiprocessorCount, 0);
    bool coop = (e1 == hipSuccess && e2 == hipSuccess && nb > 0 && ncu > 0 &&
                 (long)nb * ncu >= NBLK);
    if (coop) {
        hipMemsetAsync(bar, 0, 64, stream);   // zero barrier counter (graph-safe)
        void* args[] = {(void*)&x, (void*)&d, (void*)&out, (void*)&dn,
                        (void*)&rp0, (void*)&rp1, (void*)&recon,
                        (void*)&segval, (void*)&segidx,
                        (void*)&abv0, (void*)&abi0, (void*)&abv1, (void*)&abi1,
                        (void*)&bar};
        hipError_t e = hipLaunchCooperativeKernel((const void*)k_coop, dim3(NBLK), dim3(256),
                                                  args, 0, stream);
        if (e == hipSuccess) return;
    }
    // fallback: same device code, separate launches, double-buffered (race-free)
    k_f_norm_init<<<NBLK, 256, 0, stream>>>(x, d, dn, rp0, recon);
    k_f_conv<<<NBLK, 256, 0, stream>>>(rp0, dn, segval, segidx, abv0, abi0);
    float* rbuf[2] = {rp0, rp1};
    float* av[2]   = {abv0, abv1};
    int*   ai[2]   = {abi0, abi1};
    for (int it = 0; it < ITERS; it++) {
        k_f_iter<<<NBLK, 256, 0, stream>>>(it == ITERS-1 ? 1 : 0,
                                           av[it & 1], ai[it & 1],
                                           av[(it + 1) & 1], ai[(it + 1) & 1],
                                           rbuf[it & 1], rbuf[(it + 1) & 1],
                                           recon, dn, segval, segidx);
    }
    k_f_out<<<(B*T + 255)/256, 256, 0, stream>>>(recon, out);
}